// Round 2
// baseline (1535.951 us; speedup 1.0000x reference)
//
#include <hip/hip_runtime.h>

// ---------------------------------------------------------------------------
// CNN_quantize: quantize (VQ w/ softmax att) -> conv5x5 relu -> conv5x5 pool
// relu -> conv5x5 pool relu -> fc relu -> fc.  All f32 this round.
//
// Output layout (floats): [0,1280) pred(128,10); [1280] extra_loss;
// [1281, 1281+84934656) att(3,221184,128); [84935937] contrastive(=0).
//
// Workspace layout (floats):
//   xq   @ 0          : 128*3*96*96   = 3,538,944
//   y1   @ 3538944    : 128*32*92*92  = 34,668,544
//   y2   @ 38207488   : 128*32*44*44  = 7,929,856
//   y3   @ 46137344   : 128*16*20*20  = 819,200
//   part @ 46956544   : 16*128*512    = 1,048,576
//   y4   @ 48005120   : 128*512      = 65,536
//   loss @ 48070656   : 1
// total ~183.4 MB
// ---------------------------------------------------------------------------

#define NP 221184

static const size_t XQ_OFF   = 0;
static const size_t Y1_OFF   = 3538944;
static const size_t Y2_OFF   = Y1_OFF + 34668544;   // 38,207,488
static const size_t Y3_OFF   = Y2_OFF + 7929856;    // 46,137,344
static const size_t PART_OFF = Y3_OFF + 819200;     // 46,956,544
static const size_t Y4_OFF   = PART_OFF + 1048576;  // 48,005,120
static const size_t LOSS_OFF = Y4_OFF + 65536;      // 48,070,656

// ---------------------------------------------------------------------- quant
__global__ __launch_bounds__(256) void quant_kernel(
    const float* __restrict__ x, const float* __restrict__ cb,
    float* __restrict__ att, float* __restrict__ xq, float* __restrict__ lossAcc)
{
  __shared__ float cbT[3][16][128];   // [g][d][k] transposed: conflict-free k-reads
  __shared__ float cbRM[3][128][16];  // [g][k][d] row-major: for gather
  __shared__ float cbn2[3][128];

  for (int t = threadIdx.x; t < 3*128*16; t += 256) {
    float v = cb[t];
    int g = t >> 11, k = (t >> 4) & 127, d = t & 15;
    cbRM[g][k][d] = v; cbT[g][d][k] = v;
  }
  __syncthreads();
  for (int t = threadIdx.x; t < 384; t += 256) {
    int g = t >> 7, k = t & 127;
    float s = 0.f;
#pragma unroll
    for (int d = 0; d < 16; ++d) { float c = cbRM[g][k][d]; s += c*c; }
    cbn2[g][k] = s;
  }
  __syncthreads();

  int lane = threadIdx.x & 63;
  int gw = (blockIdx.x << 2) + (threadIdx.x >> 6);
  int nw = gridDim.x << 2;
  float lossLocal = 0.f;

  for (int n = gw; n < NP; n += nw) {
    const float* xp = x + (size_t)n * 16;
    float xv[16];
    float xn2 = 0.f;
#pragma unroll
    for (int d = 0; d < 16; ++d) { xv[d] = xp[d]; xn2 += xv[d]*xv[d]; }

    int idxg0 = 0, idxg1 = 0, idxg2 = 0;
#pragma unroll
    for (int g = 0; g < 3; ++g) {
      float dot0 = 0.f, dot1 = 0.f;
#pragma unroll
      for (int d = 0; d < 16; ++d) {
        dot0 += xv[d] * cbT[g][d][lane];
        dot1 += xv[d] * cbT[g][d][lane + 64];
      }
      float d2a = xn2 - 2.f*dot0 + cbn2[g][lane];
      float d2b = xn2 - 2.f*dot1 + cbn2[g][lane + 64];
      // argmin over 128 (tie -> lower index, matches jnp.argmin)
      float mv = d2a; int mi = lane;
      if (d2b < mv) { mv = d2b; mi = lane + 64; }
#pragma unroll
      for (int off = 32; off > 0; off >>= 1) {
        float ov = __shfl_xor(mv, off);
        int   oi = __shfl_xor(mi, off);
        if (ov < mv || (ov == mv && oi < mi)) { mv = ov; mi = oi; }
      }
      // softmax(-d2): exp(mv - d2)/sum
      float e0 = __expf(mv - d2a);
      float e1 = __expf(mv - d2b);
      float s = e0 + e1;
#pragma unroll
      for (int off = 32; off > 0; off >>= 1) s += __shfl_xor(s, off);
      float inv = 1.f / s;
      float* ab = att + ((size_t)g * NP + n) * 128;
      ab[lane]      = e0 * inv;
      ab[lane + 64] = e1 * inv;
      if (g == 0) idxg0 = mi; else if (g == 1) idxg1 = mi; else idxg2 = mi;
    }

    if (lane < 16) {
      float q0 = cbRM[0][idxg0][lane];
      float q1 = cbRM[1][idxg1][lane];
      float q2 = cbRM[2][idxg2][lane];
      xq[(size_t)n*16 + lane] = (q0 + q1 + q2) * (1.f/3.f);
      float a = q0 - xv[lane], b = q1 - xv[lane], c = q2 - xv[lane];
      lossLocal += a*a + b*b + c*c;
    }
  }
#pragma unroll
  for (int off = 32; off > 0; off >>= 1) lossLocal += __shfl_xor(lossLocal, off);
  if (lane == 0) atomicAdd(lossAcc, lossLocal);
}

// ----------------------------------------------------------------------- conv
// Direct 5x5 VALID conv, optional fused 2x2 maxpool, fused bias+relu.
// Block: 256 threads = OCB oc x 16 slots; each thread: 2 rows x 8 cols pre-pool.
// Pre-pool tile 8x32. POOL: stores 4x16 pooled tile.
template<int IC, int OC, int IH, int IW, bool POOL, int ICB, int OCB>
__global__ __launch_bounds__(256) void conv5x5(
    const float* __restrict__ in, const float* __restrict__ wgt,
    const float* __restrict__ bias, float* __restrict__ out)
{
  constexpr int OHH = IH - 4, OWW = IW - 4;
  constexpr int PH = POOL ? OHH/2 : OHH, PW = POOL ? OWW/2 : OWW;
  constexpr int TPH = POOL ? 4 : 8, TPW = POOL ? 16 : 32;
  constexpr int NTX = (PW + TPW - 1) / TPW;

  int tile = blockIdx.x;
  int tx0 = (tile % NTX) * TPW, ty0 = (tile / NTX) * TPH;
  int ocg = blockIdx.y, n = blockIdx.z;
  int oy0 = POOL ? ty0*2 : ty0;
  int ox0 = POOL ? tx0*2 : tx0;

  int oc_l = threadIdx.x & (OCB - 1);
  int slot = threadIdx.x / OCB;       // 0..15
  int rp = slot >> 2;                 // row-pair 0..3
  int cs = slot & 3;                  // col-strip 0..3

  __shared__ __align__(16) float ins[ICB][12][36];
  __shared__ float wl[OCB][ICB*25 + 1];

  float acc[2][8];
#pragma unroll
  for (int r = 0; r < 2; ++r)
#pragma unroll
    for (int p = 0; p < 8; ++p) acc[r][p] = 0.f;

  constexpr int IN_ELEMS = ICB * 12 * 36;
  constexpr int W_ELEMS  = OCB * ICB * 25;

#pragma unroll 1
  for (int icc = 0; icc < IC; icc += ICB) {
    for (int t = threadIdx.x; t < IN_ELEMS; t += 256) {
      int ic = t / (12*36); int r = t % (12*36); int ry = r / 36, rx = r % 36;
      int gy = oy0 + ry, gx = ox0 + rx;
      float v = 0.f;
      if (gy < IH && gx < IW)
        v = in[(((size_t)n*IC + icc + ic)*IH + gy)*IW + gx];
      ins[ic][ry][rx] = v;
    }
    for (int t = threadIdx.x; t < W_ELEMS; t += 256) {
      int oc = t / (ICB*25); int r = t % (ICB*25);
      wl[oc][r] = wgt[((size_t)(ocg*OCB + oc)*IC + icc)*25 + r];
    }
    __syncthreads();

#pragma unroll 1
    for (int ic = 0; ic < ICB; ++ic) {
#pragma unroll
      for (int ky = 0; ky < 5; ++ky) {
        float wv[5];
#pragma unroll
        for (int kx = 0; kx < 5; ++kx) wv[kx] = wl[oc_l][ic*25 + ky*5 + kx];
#pragma unroll
        for (int rr = 0; rr < 2; ++rr) {
          int ry = 2*rp + rr + ky;
          const float4* rowp = (const float4*)&ins[ic][ry][cs*8];
          float4 a = rowp[0], b = rowp[1], c = rowp[2];
          float iv[12] = {a.x,a.y,a.z,a.w, b.x,b.y,b.z,b.w, c.x,c.y,c.z,c.w};
#pragma unroll
          for (int kx = 0; kx < 5; ++kx)
#pragma unroll
            for (int px = 0; px < 8; ++px)
              acc[rr][px] += iv[px + kx] * wv[kx];
        }
      }
    }
    __syncthreads();
  }

  float bv = bias[ocg*OCB + oc_l];
  if (POOL) {
    int pr = ty0 + rp, pc = tx0 + cs*4;
    if (pr < PH && pc < PW) {   // PW%4==0 -> strip fully in or out
      float4 v; float* vp = &v.x;
#pragma unroll
      for (int j = 0; j < 4; ++j) {
        float m01 = fmaxf(acc[0][2*j], acc[0][2*j+1]);
        float m23 = fmaxf(acc[1][2*j], acc[1][2*j+1]);
        vp[j] = fmaxf(fmaxf(m01, m23) + bv, 0.f);
      }
      *(float4*)&out[(((size_t)n*OC + ocg*OCB + oc_l)*PH + pr)*PW + pc] = v;
    }
  } else {
#pragma unroll
    for (int rr = 0; rr < 2; ++rr) {
      int oy = oy0 + 2*rp + rr;
      if (oy >= OHH) continue;
#pragma unroll
      for (int h = 0; h < 2; ++h) {
        int ox = ox0 + cs*8 + 4*h;
        size_t base = (((size_t)n*OC + ocg*OCB + oc_l)*OHH + oy)*OWW;
        if (ox + 3 < OWW) {
          float4 v; float* vp = &v.x;
#pragma unroll
          for (int j = 0; j < 4; ++j) vp[j] = fmaxf(acc[rr][4*h+j] + bv, 0.f);
          *(float4*)&out[base + ox] = v;
        } else {
#pragma unroll
          for (int j = 0; j < 4; ++j) {
            int oxx = ox + j;
            if (oxx < OWW) out[base + oxx] = fmaxf(acc[rr][4*h+j] + bv, 0.f);
          }
        }
      }
    }
  }
}

// ------------------------------------------------------------------------ fc1
// Split-K partials: grid (nt=16, ks=16); block computes 128m x 32n over K=400.
__global__ __launch_bounds__(256) void fc1_partial(
    const float* __restrict__ x, const float* __restrict__ w,
    float* __restrict__ part)
{
  constexpr int KC = 6400 / 16;   // 400
  __shared__ float xl[128][16];
  __shared__ float wlds[32][17];
  int nt = blockIdx.x, ks = blockIdx.y;
  int k0 = ks * KC;
  int nl = threadIdx.x & 31;
  int mg = threadIdx.x >> 5;      // 0..7
  float acc[16];
#pragma unroll
  for (int j = 0; j < 16; ++j) acc[j] = 0.f;

  for (int kb = 0; kb < KC; kb += 16) {
    for (int t = threadIdx.x; t < 128*16; t += 256) {
      int m = t >> 4, kk = t & 15;
      xl[m][kk] = x[(size_t)m*6400 + k0 + kb + kk];
    }
    for (int t = threadIdx.x; t < 32*16; t += 256) {
      int nn = t >> 4, kk = t & 15;
      wlds[nn][kk] = w[(size_t)(nt*32 + nn)*6400 + k0 + kb + kk];
    }
    __syncthreads();
#pragma unroll
    for (int kk = 0; kk < 16; ++kk) {
      float wv = wlds[nl][kk];
#pragma unroll
      for (int j = 0; j < 16; ++j)
        acc[j] += xl[mg + 8*j][kk] * wv;
    }
    __syncthreads();
  }
#pragma unroll
  for (int j = 0; j < 16; ++j) {
    int m = mg + 8*j;
    part[((size_t)ks*128 + m)*512 + nt*32 + nl] = acc[j];
  }
}

__global__ __launch_bounds__(256) void fc1_reduce(
    const float* __restrict__ part, const float* __restrict__ bias,
    float* __restrict__ y4)
{
  int o = blockIdx.x*256 + threadIdx.x;   // 65536
  int n = o & 511;
  float s = 0.f;
#pragma unroll
  for (int ks = 0; ks < 16; ++ks)
    s += part[(size_t)ks*65536 + o];
  y4[o] = fmaxf(s + bias[n], 0.f);
}

// ------------------------------------------------------------------------ fc2
__global__ __launch_bounds__(256) void fc2_kernel(
    const float* __restrict__ y4, const float* __restrict__ w2,
    const float* __restrict__ b2, float* __restrict__ pred)
{
  int o = blockIdx.x*256 + threadIdx.x;
  if (o >= 1280) return;
  int m = o / 10, c = o % 10;
  float s = 0.f;
  const float* yr = y4 + (size_t)m*512;
  const float* wr = w2 + (size_t)c*512;
#pragma unroll 8
  for (int k = 0; k < 512; ++k) s += yr[k]*wr[k];
  pred[o] = s + b2[c];
}

// -------------------------------------------------------------------- epilogue
__global__ void finalize_kernel(const float* __restrict__ lossAcc,
                                float* __restrict__ out)
{
  // extra_loss = (1+ALPHA) * mean((q-xp)^2) over 3*221184*16 elems
  out[1280] = 2.f * (*lossAcc) / 10616832.f;
  out[84935937] = 0.f;   // contrastive
}

// ---------------------------------------------------------------------- launch
extern "C" void kernel_launch(void* const* d_in, const int* in_sizes, int n_in,
                              void* d_out, int out_size, void* d_ws, size_t ws_size,
                              hipStream_t stream)
{
  const float* x   = (const float*)d_in[0];
  const float* cb  = (const float*)d_in[1];
  const float* w1  = (const float*)d_in[2];
  const float* b1  = (const float*)d_in[3];
  const float* w2  = (const float*)d_in[4];
  const float* b2  = (const float*)d_in[5];
  const float* w3  = (const float*)d_in[6];
  const float* b3  = (const float*)d_in[7];
  const float* wf1 = (const float*)d_in[8];
  const float* bf1 = (const float*)d_in[9];
  const float* wf2 = (const float*)d_in[10];
  const float* bf2 = (const float*)d_in[11];

  float* out  = (float*)d_out;
  float* ws   = (float*)d_ws;
  float* xq   = ws + XQ_OFF;
  float* y1   = ws + Y1_OFF;
  float* y2   = ws + Y2_OFF;
  float* y3   = ws + Y3_OFF;
  float* part = ws + PART_OFF;
  float* y4   = ws + Y4_OFF;
  float* loss = ws + LOSS_OFF;

  hipMemsetAsync(loss, 0, sizeof(float), stream);

  // quantize: att -> out+1281, xq -> ws
  quant_kernel<<<768, 256, 0, stream>>>(x, cb, out + 1281, xq, loss);

  // conv1: (128,3,96,96)->(128,32,92,92), relu.  tiles: NTX=3, NTY=12 -> 36
  conv5x5<3, 32, 96, 96, false, 3, 16><<<dim3(36, 2, 128), 256, 0, stream>>>(xq, w1, b1, y1);
  // conv2: (128,32,92,92)->pool->(128,32,44,44). tiles: NTX=3, NTY=11 -> 33
  conv5x5<32, 32, 92, 92, true, 16, 16><<<dim3(33, 2, 128), 256, 0, stream>>>(y1, w2, b2, y2);
  // conv3: (128,32,44,44)->pool->(128,16,20,20). tiles: NTX=2, NTY=5 -> 10
  conv5x5<32, 16, 44, 44, true, 16, 16><<<dim3(10, 1, 128), 256, 0, stream>>>(y2, w3, b3, y3);

  // fc1: (128,6400)@(512,6400)^T, split-K 16
  fc1_partial<<<dim3(16, 16), 256, 0, stream>>>(y3, wf1, part);
  fc1_reduce<<<256, 256, 0, stream>>>(part, bf1, y4);

  // fc2 -> pred
  fc2_kernel<<<5, 256, 0, stream>>>(y4, wf2, bf2, out);

  finalize_kernel<<<1, 1, 0, stream>>>(loss, out);
}

// Round 3
// 726.128 us; speedup vs baseline: 2.1153x; 2.1153x over previous
//
#include <hip/hip_runtime.h>
#include <hip/hip_bf16.h>

// ---------------------------------------------------------------------------
// CNN_quantize round 3: quant (f32) -> conv1 direct f32 (out bf16 NHWC)
//   -> conv2 MFMA bf16 implicit GEMM + fused pool/relu (NHWC)
//   -> conv3 MFMA bf16 + fused pool/relu (NHWC) -> repack -> fc1/fc2 f32.
//
// Output layout (floats): [0,1280) pred; [1280] extra_loss;
// [1281,1281+84934656) att(3,221184,128); [84935937] contrastive.
//
// Workspace (byte offsets):
//   xq   f32  @ 0           14,155,776 B   (128,3,96,96)
//   y1   bf16 @ 14,155,776  69,337,088 B   (128,92,92,32) NHWC
//   y2   bf16 @ 83,492,864  15,859,712 B   (128,44,44,32) NHWC
//   y3   bf16 @ 99,352,576   1,638,400 B   (128,20,20,16) NHWC
//   y3f  f32  @ 100,990,976  3,276,800 B   (128,6400) NCHW flat
//   part f32  @ 104,267,776  4,194,304 B
//   y4   f32  @ 108,462,080    262,144 B
//   wp2  bf16 @ 108,724,224     51,200 B   packed conv2 A-frags
//   wp3  bf16 @ 108,775,424     25,600 B   packed conv3 A-frags
//   loss f32  @ 108,801,024          4 B
// ---------------------------------------------------------------------------

#define NP 221184

typedef __attribute__((ext_vector_type(8)))  short  short8;   // 8 bf16
typedef __attribute__((ext_vector_type(16))) float  f32x16;
typedef __attribute__((ext_vector_type(4)))  float  f32x4;

// ---------------------------------------------------------------------- quant
__global__ __launch_bounds__(256) void quant_kernel(
    const float* __restrict__ x, const float* __restrict__ cb,
    float* __restrict__ att, float* __restrict__ xq, float* __restrict__ lossAcc)
{
  __shared__ float cbT[3][16][128];
  __shared__ float cbRM[3][128][16];
  __shared__ float cbn2[3][128];

  for (int t = threadIdx.x; t < 3*128*16; t += 256) {
    float v = cb[t];
    int g = t >> 11, k = (t >> 4) & 127, d = t & 15;
    cbRM[g][k][d] = v; cbT[g][d][k] = v;
  }
  __syncthreads();
  for (int t = threadIdx.x; t < 384; t += 256) {
    int g = t >> 7, k = t & 127;
    float s = 0.f;
#pragma unroll
    for (int d = 0; d < 16; ++d) { float c = cbRM[g][k][d]; s += c*c; }
    cbn2[g][k] = s;
  }
  __syncthreads();

  int lane = threadIdx.x & 63;
  int gw = (blockIdx.x << 2) + (threadIdx.x >> 6);
  int nw = gridDim.x << 2;
  float lossLocal = 0.f;

  for (int n = gw; n < NP; n += nw) {
    const float* xp = x + (size_t)n * 16;
    float xv[16];
    float xn2 = 0.f;
#pragma unroll
    for (int d = 0; d < 16; ++d) { xv[d] = xp[d]; xn2 += xv[d]*xv[d]; }

    int idxg0 = 0, idxg1 = 0, idxg2 = 0;
#pragma unroll
    for (int g = 0; g < 3; ++g) {
      float dot0 = 0.f, dot1 = 0.f;
#pragma unroll
      for (int d = 0; d < 16; ++d) {
        dot0 += xv[d] * cbT[g][d][lane];
        dot1 += xv[d] * cbT[g][d][lane + 64];
      }
      float d2a = xn2 - 2.f*dot0 + cbn2[g][lane];
      float d2b = xn2 - 2.f*dot1 + cbn2[g][lane + 64];
      float mv = d2a; int mi = lane;
      if (d2b < mv) { mv = d2b; mi = lane + 64; }
#pragma unroll
      for (int off = 32; off > 0; off >>= 1) {
        float ov = __shfl_xor(mv, off);
        int   oi = __shfl_xor(mi, off);
        if (ov < mv || (ov == mv && oi < mi)) { mv = ov; mi = oi; }
      }
      float e0 = __expf(mv - d2a);
      float e1 = __expf(mv - d2b);
      float s = e0 + e1;
#pragma unroll
      for (int off = 32; off > 0; off >>= 1) s += __shfl_xor(s, off);
      float inv = 1.f / s;
      float* ab = att + ((size_t)g * NP + n) * 128;
      ab[lane]      = e0 * inv;
      ab[lane + 64] = e1 * inv;
      if (g == 0) idxg0 = mi; else if (g == 1) idxg1 = mi; else idxg2 = mi;
    }

    if (lane < 16) {
      float q0 = cbRM[0][idxg0][lane];
      float q1 = cbRM[1][idxg1][lane];
      float q2 = cbRM[2][idxg2][lane];
      xq[(size_t)n*16 + lane] = (q0 + q1 + q2) * (1.f/3.f);
      float a = q0 - xv[lane], b = q1 - xv[lane], c = q2 - xv[lane];
      lossLocal += a*a + b*b + c*c;
    }
  }
#pragma unroll
  for (int off = 32; off > 0; off >>= 1) lossLocal += __shfl_xor(lossLocal, off);
  if (lane == 0) atomicAdd(lossAcc, lossLocal);
}

// ----------------------------------------------------------------- weight pack
// wp2: [ks=50][lane=64][8 bf16]  k-order (ky,kx,ih); ic = ih*16 + (lane>>5)*8 + j
// wp3: [ks=25][lane=64][8 bf16]  k-order (ky,kx);    ic = (lane>>4)*8 + j
__global__ __launch_bounds__(256) void pack_w_kernel(
    const float* __restrict__ w2, const float* __restrict__ w3,
    __hip_bfloat16* __restrict__ p2, __hip_bfloat16* __restrict__ p3)
{
  int t = blockIdx.x*256 + threadIdx.x;
  if (t < 25600) {
    int ks = t >> 9, l = (t >> 3) & 63, j = t & 7;
    int ky = ks/10, kx = (ks%10)>>1, ih = ks & 1;
    int oc = l & 31, kh = l >> 5;
    int ic = ih*16 + kh*8 + j;
    p2[t] = __float2bfloat16(w2[((oc*32 + ic)*5 + ky)*5 + kx]);
  }
  if (t < 12800) {
    int ks = t >> 9, l = (t >> 3) & 63, j = t & 7;
    int ky = ks/5, kx = ks%5;
    int oc = l & 15, kh = l >> 4;
    int ic = kh*8 + j;
    p3[t] = __float2bfloat16(w3[((oc*32 + ic)*5 + ky)*5 + kx]);
  }
}

// ---------------------------------------------------------------- conv1 direct
// (128,3,96,96) f32 NCHW -> (128,92,92,32) bf16 NHWC, relu.
// grid (36 = 3x x 12y, 2 ocg, 128 n), 256 thr. Tile 8 rows x 32 cols, 16 oc.
__global__ __launch_bounds__(256) void conv1_kernel(
    const float* __restrict__ in, const float* __restrict__ wgt,
    const float* __restrict__ bias, __hip_bfloat16* __restrict__ out)
{
  int tile = blockIdx.x;
  int tx0 = (tile % 3) * 32, ty0 = (tile / 3) * 8;
  int ocg = blockIdx.y, n = blockIdx.z;

  int oc_l = threadIdx.x & 15;
  int slot = threadIdx.x >> 4;        // 0..15
  int rp = slot >> 2, cs = slot & 3;

  __shared__ __align__(16) float ins[3][12][36];
  __shared__ float wl[16][76];
  __shared__ __hip_bfloat16 tb[8][32][16];   // 8KB transpose buffer

  float acc[2][8];
#pragma unroll
  for (int r = 0; r < 2; ++r)
#pragma unroll
    for (int p = 0; p < 8; ++p) acc[r][p] = 0.f;

  for (int t = threadIdx.x; t < 3*12*36; t += 256) {
    int ic = t / (12*36); int r = t % (12*36); int ry = r / 36, rx = r % 36;
    int gy = ty0 + ry, gx = tx0 + rx;
    float v = 0.f;
    if (gy < 96 && gx < 96)
      v = in[(((size_t)n*3 + ic)*96 + gy)*96 + gx];
    ins[ic][ry][rx] = v;
  }
  for (int t = threadIdx.x; t < 16*75; t += 256) {
    int oc = t / 75, r = t % 75;
    wl[oc][r] = wgt[(size_t)(ocg*16 + oc)*75 + r];
  }
  __syncthreads();

#pragma unroll 1
  for (int ic = 0; ic < 3; ++ic) {
#pragma unroll
    for (int ky = 0; ky < 5; ++ky) {
      float wv[5];
#pragma unroll
      for (int kx = 0; kx < 5; ++kx) wv[kx] = wl[oc_l][ic*25 + ky*5 + kx];
#pragma unroll
      for (int rr = 0; rr < 2; ++rr) {
        int ry = 2*rp + rr + ky;
        const float4* rowp = (const float4*)&ins[ic][ry][cs*8];
        float4 a = rowp[0], b = rowp[1], c = rowp[2];
        float iv[12] = {a.x,a.y,a.z,a.w, b.x,b.y,b.z,b.w, c.x,c.y,c.z,c.w};
#pragma unroll
        for (int kx = 0; kx < 5; ++kx)
#pragma unroll
          for (int px = 0; px < 8; ++px)
            acc[rr][px] += iv[px + kx] * wv[kx];
      }
    }
  }
  __syncthreads();  // done with ins reads before tb overlap is irrelevant (separate buffers), but order anyway

  float bv = bias[ocg*16 + oc_l];
#pragma unroll
  for (int rr = 0; rr < 2; ++rr)
#pragma unroll
    for (int px = 0; px < 8; ++px)
      tb[2*rp + rr][cs*8 + px][oc_l] = __float2bfloat16(fmaxf(acc[rr][px] + bv, 0.f));
  __syncthreads();

  for (int t = threadIdx.x; t < 512; t += 256) {
    int byte = t * 16;
    int row = byte >> 10, col = (byte & 1023) >> 5, half = (byte >> 4) & 1;
    int gy = ty0 + row, gx = tx0 + col;
    if (gy < 92 && gx < 92) {
      *(int4*)((char*)out + ((((size_t)n*92 + gy)*92 + gx)*32 + ocg*16 + half*8)*2) =
          *(const int4*)((const char*)tb + byte);
    }
  }
}

// ------------------------------------------------------------------ conv2 MFMA
// (128,92,92,32) bf16 NHWC -> conv 5x5 (88x88) -> pool -> relu
//   -> (128,44,44,32) bf16 NHWC.
// Block: 384 thr = 6 waves (rp in {0,1}, cg in {0,1,2}); 4 out rows x 96 cols.
// K = 50 steps of 16 (ky,kx,ih); mfma_f32_32x32x16_bf16; A from global (packed).
__global__ __launch_bounds__(384) void conv2_mfma(
    const __hip_bfloat16* __restrict__ in, const __hip_bfloat16* __restrict__ wp,
    const float* __restrict__ bias, __hip_bfloat16* __restrict__ out)
{
  __shared__ __align__(16) char lds[8*100*64];   // 51200 B, NHWC pixels swizzled

  int n = blockIdx.y, rg = blockIdx.x;
  int oy0 = rg * 4;
  int tid = threadIdx.x;

  // stage 8 rows x 100 px x 4 granules(16B)
  for (int t = tid; t < 3200; t += 384) {
    int row = t / 400, rem = t % 400, px = rem >> 2, g = rem & 3;
    int4 v = make_int4(0,0,0,0);
    if (px < 92)
      v = *(const int4*)(in + (((size_t)n*92 + oy0 + row)*92 + px)*32 + g*8);
    int sb = ((row*100 + px) << 6) + ((g ^ ((px >> 1) & 3)) << 4);
    *(int4*)(lds + sb) = v;
  }
  __syncthreads();

  int wv = tid >> 6, lane = tid & 63;
  int rp = wv & 1, cg = wv >> 1;
  int col = lane & 31, khalf = lane >> 5;
  int ixb = cg*32 + col;

  f32x16 acc0, acc1;
#pragma unroll
  for (int i = 0; i < 16; ++i) { acc0[i] = 0.f; acc1[i] = 0.f; }

#pragma unroll
  for (int ks = 0; ks < 50; ++ks) {
    const int ky = ks/10, kx = (ks%10)>>1, ih = ks & 1;
    short8 av = *(const short8*)(wp + ks*512 + lane*8);
    int ix = ixb + kx;
    int g  = (ih*2 + khalf) ^ ((ix >> 1) & 3);
    {
      int row = 2*rp + 0 + ky;
      short8 bv = *(const short8*)(lds + ((row*100 + ix) << 6) + (g << 4));
      acc0 = __builtin_amdgcn_mfma_f32_32x32x16_bf16(av, bv, acc0, 0, 0, 0);
    }
    {
      int row = 2*rp + 1 + ky;
      short8 bv = *(const short8*)(lds + ((row*100 + ix) << 6) + (g << 4));
      acc1 = __builtin_amdgcn_mfma_f32_32x32x16_bf16(av, bv, acc1, 0, 0, 0);
    }
  }
  __syncthreads();   // all waves done reading input LDS

  // pool 2x2 + bias + relu; write pooled [wave][16px][32oc] bf16 into lds
  {
#pragma unroll
    for (int rq = 0; rq < 4; ++rq) {
      __hip_bfloat16 pv[4];
#pragma unroll
      for (int rr = 0; rr < 4; ++rr) {
        int r = rq*4 + rr;
        float m = fmaxf(acc0[r], acc1[r]);
        float o = __shfl_xor(m, 1);
        float p = fmaxf(m, o);
        int oc = (r & 3) + 8*(r >> 2) + 4*khalf;
        pv[rr] = __float2bfloat16(fmaxf(p + bias[oc], 0.f));
      }
      if ((lane & 1) == 0) {
        int pl = col >> 1;   // 0..15
        // oc base for this rq-group: (0..3)+8*rq+4*khalf
        *(uint2*)(lds + wv*1024 + pl*64 + (8*rq + 4*khalf)*2) = *(const uint2*)pv;
      }
    }
  }
  __syncthreads();

  // store: 6 waves x 1KB; granule t -> 16B
  if (tid < 384) {
    int byte = tid * 16;
    int w = byte >> 10, r = byte & 1023;
    int pl = r >> 6, ocq = (r & 63) >> 4;
    int pr = rg*2 + (w & 1);
    int pc = (w >> 1)*16 + pl;
    if (pc < 44) {
      *(int4*)(out + (((size_t)n*44 + pr)*44 + pc)*32 + ocq*8) =
          *(const int4*)(lds + byte);
    }
  }
}

// ------------------------------------------------------------------ conv3 MFMA
// (128,44,44,32) bf16 NHWC -> conv 5x5 (40x40) -> pool -> relu
//   -> (128,20,20,16) bf16 NHWC.
// Block: 384 thr = 6 waves (rp, cg); 4 out rows x 48 cols (40 valid).
// K = 25 steps of 32 (ky,kx); mfma_f32_16x16x32_bf16.
__global__ __launch_bounds__(384) void conv3_mfma(
    const __hip_bfloat16* __restrict__ in, const __hip_bfloat16* __restrict__ wp,
    const float* __restrict__ bias, __hip_bfloat16* __restrict__ out)
{
  __shared__ __align__(16) char lds[8*52*64];   // 26624 B

  int n = blockIdx.y, rg = blockIdx.x;
  int oy0 = rg * 4;
  int tid = threadIdx.x;

  for (int t = tid; t < 1664; t += 384) {
    int row = t / 208, rem = t % 208, px = rem >> 2, g = rem & 3;
    int4 v = make_int4(0,0,0,0);
    if (px < 44)
      v = *(const int4*)(in + (((size_t)n*44 + oy0 + row)*44 + px)*32 + g*8);
    int sb = ((row*52 + px) << 6) + ((g ^ ((px >> 1) & 3)) << 4);
    *(int4*)(lds + sb) = v;
  }
  __syncthreads();

  int wv = tid >> 6, lane = tid & 63;
  int rp = wv & 1, cg = wv >> 1;
  int col = lane & 15, kq = lane >> 4;     // kq 0..3
  int ixb = cg*16 + col;

  f32x4 acc0, acc1;
#pragma unroll
  for (int i = 0; i < 4; ++i) { acc0[i] = 0.f; acc1[i] = 0.f; }

#pragma unroll
  for (int ks = 0; ks < 25; ++ks) {
    const int ky = ks/5, kx = ks%5;
    short8 av = *(const short8*)(wp + ks*512 + lane*8);
    int ix = ixb + kx;
    int g  = kq ^ ((ix >> 1) & 3);
    {
      int row = 2*rp + 0 + ky;
      short8 bv = *(const short8*)(lds + ((row*52 + ix) << 6) + (g << 4));
      acc0 = __builtin_amdgcn_mfma_f32_16x16x32_bf16(av, bv, acc0, 0, 0, 0);
    }
    {
      int row = 2*rp + 1 + ky;
      short8 bv = *(const short8*)(lds + ((row*52 + ix) << 6) + (g << 4));
      acc1 = __builtin_amdgcn_mfma_f32_16x16x32_bf16(av, bv, acc1, 0, 0, 0);
    }
  }
  __syncthreads();

  // pool + bias + relu -> lds [wave][8px][16oc]
  {
    __hip_bfloat16 pv[4];
#pragma unroll
    for (int r = 0; r < 4; ++r) {
      float m = fmaxf(acc0[r], acc1[r]);
      float o = __shfl_xor(m, 1);
      float p = fmaxf(m, o);
      int oc = kq*4 + r;
      pv[r] = __float2bfloat16(fmaxf(p + bias[oc], 0.f));
    }
    if ((lane & 1) == 0) {
      int pl = col >> 1;   // 0..7
      *(uint2*)(lds + wv*256 + pl*32 + kq*8) = *(const uint2*)pv;
    }
  }
  __syncthreads();

  if (tid < 96) {
    int byte = tid * 16;
    int w = byte >> 8, r = byte & 255;
    int pl = r >> 5, half = (r & 31) >> 4;
    int pr = rg*2 + (w & 1);
    int pc = (w >> 1)*8 + pl;
    if (pc < 20) {
      *(int4*)(out + (((size_t)n*20 + pr)*20 + pc)*16 + half*8) =
          *(const int4*)(lds + byte);
    }
  }
}

// --------------------------------------------------------------------- repack
__global__ __launch_bounds__(256) void repack_y3(
    const __hip_bfloat16* __restrict__ y3, float* __restrict__ y3f)
{
  int t = blockIdx.x*256 + threadIdx.x;
  if (t < 819200) {
    int c = t & 15; int r = t >> 4;
    int x = r % 20; r /= 20;
    int y = r % 20; int m = r / 20;
    y3f[((size_t)m*16 + c)*400 + y*20 + x] = __bfloat162float(y3[t]);
  }
}

// ------------------------------------------------------------------------ fc1
__global__ __launch_bounds__(256) void fc1_partial(
    const float* __restrict__ x, const float* __restrict__ w,
    float* __restrict__ part)
{
  constexpr int KC = 6400 / 16;
  __shared__ float xl[128][16];
  __shared__ float wlds[32][17];
  int nt = blockIdx.x, ks = blockIdx.y;
  int k0 = ks * KC;
  int nl = threadIdx.x & 31;
  int mg = threadIdx.x >> 5;
  float acc[16];
#pragma unroll
  for (int j = 0; j < 16; ++j) acc[j] = 0.f;

  for (int kb = 0; kb < KC; kb += 16) {
    for (int t = threadIdx.x; t < 128*16; t += 256) {
      int m = t >> 4, kk = t & 15;
      xl[m][kk] = x[(size_t)m*6400 + k0 + kb + kk];
    }
    for (int t = threadIdx.x; t < 32*16; t += 256) {
      int nn = t >> 4, kk = t & 15;
      wlds[nn][kk] = w[(size_t)(nt*32 + nn)*6400 + k0 + kb + kk];
    }
    __syncthreads();
#pragma unroll
    for (int kk = 0; kk < 16; ++kk) {
      float wvv = wlds[nl][kk];
#pragma unroll
      for (int j = 0; j < 16; ++j)
        acc[j] += xl[mg + 8*j][kk] * wvv;
    }
    __syncthreads();
  }
#pragma unroll
  for (int j = 0; j < 16; ++j) {
    int m = mg + 8*j;
    part[((size_t)ks*128 + m)*512 + nt*32 + nl] = acc[j];
  }
}

__global__ __launch_bounds__(256) void fc1_reduce(
    const float* __restrict__ part, const float* __restrict__ bias,
    float* __restrict__ y4)
{
  int o = blockIdx.x*256 + threadIdx.x;
  int nn = o & 511;
  float s = 0.f;
#pragma unroll
  for (int ks = 0; ks < 16; ++ks)
    s += part[(size_t)ks*65536 + o];
  y4[o] = fmaxf(s + bias[nn], 0.f);
}

// ------------------------------------------------------------------------ fc2
__global__ __launch_bounds__(256) void fc2_kernel(
    const float* __restrict__ y4, const float* __restrict__ w2,
    const float* __restrict__ b2, float* __restrict__ pred)
{
  int o = blockIdx.x*256 + threadIdx.x;
  if (o >= 1280) return;
  int m = o / 10, c = o % 10;
  float s = 0.f;
  const float* yr = y4 + (size_t)m*512;
  const float* wr = w2 + (size_t)c*512;
#pragma unroll 8
  for (int k = 0; k < 512; ++k) s += yr[k]*wr[k];
  pred[o] = s + b2[c];
}

// -------------------------------------------------------------------- epilogue
__global__ void finalize_kernel(const float* __restrict__ lossAcc,
                                float* __restrict__ out)
{
  out[1280] = 2.f * (*lossAcc) / 10616832.f;
  out[84935937] = 0.f;
}

// ---------------------------------------------------------------------- launch
extern "C" void kernel_launch(void* const* d_in, const int* in_sizes, int n_in,
                              void* d_out, int out_size, void* d_ws, size_t ws_size,
                              hipStream_t stream)
{
  const float* x   = (const float*)d_in[0];
  const float* cb  = (const float*)d_in[1];
  const float* w1  = (const float*)d_in[2];
  const float* b1  = (const float*)d_in[3];
  const float* w2  = (const float*)d_in[4];
  const float* b2  = (const float*)d_in[5];
  const float* w3  = (const float*)d_in[6];
  const float* b3  = (const float*)d_in[7];
  const float* wf1 = (const float*)d_in[8];
  const float* bf1 = (const float*)d_in[9];
  const float* wf2 = (const float*)d_in[10];
  const float* bf2 = (const float*)d_in[11];

  float* out = (float*)d_out;
  char*  ws  = (char*)d_ws;

  float*          xq   = (float*)         (ws + 0);
  __hip_bfloat16* y1   = (__hip_bfloat16*)(ws + 14155776);
  __hip_bfloat16* y2   = (__hip_bfloat16*)(ws + 83492864);
  __hip_bfloat16* y3   = (__hip_bfloat16*)(ws + 99352576);
  float*          y3f  = (float*)         (ws + 100990976);
  float*          part = (float*)         (ws + 104267776);
  float*          y4   = (float*)         (ws + 108462080);
  __hip_bfloat16* wp2  = (__hip_bfloat16*)(ws + 108724224);
  __hip_bfloat16* wp3  = (__hip_bfloat16*)(ws + 108775424);
  float*          loss = (float*)         (ws + 108801024);

  hipMemsetAsync(loss, 0, sizeof(float), stream);

  quant_kernel<<<768, 256, 0, stream>>>(x, cb, out + 1281, xq, loss);
  pack_w_kernel<<<100, 256, 0, stream>>>(w2, w3, wp2, wp3);

  conv1_kernel<<<dim3(36, 2, 128), 256, 0, stream>>>(xq, w1, b1, y1);
  conv2_mfma<<<dim3(22, 128), 384, 0, stream>>>(y1, wp2, b2, y2);
  conv3_mfma<<<dim3(10, 128), 384, 0, stream>>>(y2, wp3, b3, y3);

  repack_y3<<<3200, 256, 0, stream>>>(y3, y3f);

  fc1_partial<<<dim3(16, 16), 256, 0, stream>>>(y3f, wf1, part);
  fc1_reduce<<<256, 256, 0, stream>>>(part, bf1, y4);
  fc2_kernel<<<5, 256, 0, stream>>>(y4, wf2, bf2, out);

  finalize_kernel<<<1, 1, 0, stream>>>(loss, out);
}

// Round 5
// 654.934 us; speedup vs baseline: 2.3452x; 1.1087x over previous
//
#include <hip/hip_runtime.h>
#include <hip/hip_bf16.h>

// ---------------------------------------------------------------------------
// CNN_quantize round 4 (resubmit after infra failure): quant rewritten
// (half-wave patch split, float4 att stores, 26KB LDS). conv1 direct f32 ->
// bf16 NHWC; conv2/conv3 MFMA bf16; fc1/fc2 f32.  Only quant changed vs r3.
//
// Output layout (floats): [0,1280) pred; [1280] extra_loss;
// [1281,1281+84934656) att(3,221184,128); [84935937] contrastive.
//
// Workspace (byte offsets):
//   xq   f32  @ 0           14,155,776 B   (128,3,96,96)
//   y1   bf16 @ 14,155,776  69,337,088 B   (128,92,92,32) NHWC
//   y2   bf16 @ 83,492,864  15,859,712 B   (128,44,44,32) NHWC
//   y3   bf16 @ 99,352,576   1,638,400 B   (128,20,20,16) NHWC
//   y3f  f32  @ 100,990,976  3,276,800 B   (128,6400) NCHW flat
//   part f32  @ 104,267,776  4,194,304 B
//   y4   f32  @ 108,462,080    262,144 B
//   wp2  bf16 @ 108,724,224     51,200 B
//   wp3  bf16 @ 108,775,424     25,600 B
//   loss f32  @ 108,801,024          4 B
// ---------------------------------------------------------------------------

#define NP 221184

typedef __attribute__((ext_vector_type(8)))  short  short8;   // 8 bf16
typedef __attribute__((ext_vector_type(16))) float  f32x16;
typedef __attribute__((ext_vector_type(4)))  float  f32x4;

// ---------------------------------------------------------------------- quant
// Grid 1536 x 256. Wave = 2 patches (half-wave each); lane covers k=4*l5..+3.
// att store: one 1KB float4-coalesced store per (g, patch-pair).
__global__ __launch_bounds__(256) void quant_kernel(
    const float* __restrict__ x, const float* __restrict__ cb,
    float* __restrict__ att, float* __restrict__ xq, float* __restrict__ lossAcc)
{
  __shared__ float cbT[3][16][128];   // [g][d][k]
  __shared__ float cbn2[3][128];

  for (int t = threadIdx.x; t < 3*128*16; t += 256) {
    float v = cb[t];
    int g = t >> 11, k = (t >> 4) & 127, d = t & 15;
    cbT[g][d][k] = v;
  }
  __syncthreads();
  for (int t = threadIdx.x; t < 384; t += 256) {
    int g = t >> 7, k = t & 127;
    float s = 0.f;
#pragma unroll
    for (int d = 0; d < 16; ++d) { float c = cbT[g][d][k]; s += c*c; }
    cbn2[g][k] = s;
  }
  __syncthreads();

  const int tid  = threadIdx.x;
  const int lane = tid & 63;
  const int l5   = lane & 31;
  const int half = lane >> 5;                 // 0: patch n0, 1: patch n1
  const int gw = (blockIdx.x << 2) + (tid >> 6);
  const int nw = gridDim.x << 2;
  // shuffle source for fetching patch-B argmin indices to lanes 16..31
  const int srcl = (lane < 16) ? lane : ((lane < 32) ? lane + 16 : lane);

  float lossLocal = 0.f;

  for (int p = gw; p < NP/2; p += nw) {
    const int n0 = p << 1;
    const int n  = n0 + half;

    const float4* xp4 = (const float4*)(x + (size_t)n * 16);
    float4 xa = xp4[0], xb = xp4[1], xc = xp4[2], xd = xp4[3];
    float xv[16] = {xa.x,xa.y,xa.z,xa.w, xb.x,xb.y,xb.z,xb.w,
                    xc.x,xc.y,xc.z,xc.w, xd.x,xd.y,xd.z,xd.w};
    float xn2 = 0.f;
#pragma unroll
    for (int d = 0; d < 16; ++d) xn2 += xv[d]*xv[d];

    int idx0, idx1, idx2;
#pragma unroll
    for (int g = 0; g < 3; ++g) {
      float dot0 = 0.f, dot1 = 0.f, dot2 = 0.f, dot3 = 0.f;
#pragma unroll
      for (int d = 0; d < 16; ++d) {
        float4 cv = *(const float4*)&cbT[g][d][l5*4];
        dot0 += xv[d]*cv.x; dot1 += xv[d]*cv.y;
        dot2 += xv[d]*cv.z; dot3 += xv[d]*cv.w;
      }
      float4 c2 = *(const float4*)&cbn2[g][l5*4];
      float d20 = xn2 - 2.f*dot0 + c2.x;
      float d21 = xn2 - 2.f*dot1 + c2.y;
      float d22 = xn2 - 2.f*dot2 + c2.z;
      float d23 = xn2 - 2.f*dot3 + c2.w;

      // lane-local argmin (ties -> lowest k)
      float mv = d20; int mi = l5*4;
      if (d21 < mv) { mv = d21; mi = l5*4+1; }
      if (d22 < mv) { mv = d22; mi = l5*4+2; }
      if (d23 < mv) { mv = d23; mi = l5*4+3; }
      // 5-step butterfly within each half-wave (masks <= 16)
#pragma unroll
      for (int off = 16; off > 0; off >>= 1) {
        float ov = __shfl_xor(mv, off);
        int   oi = __shfl_xor(mi, off);
        if (ov < mv || (ov == mv && oi < mi)) { mv = ov; mi = oi; }
      }
      float e0 = __expf(mv - d20);
      float e1 = __expf(mv - d21);
      float e2 = __expf(mv - d22);
      float e3 = __expf(mv - d23);
      float s = (e0+e1)+(e2+e3);
#pragma unroll
      for (int off = 16; off > 0; off >>= 1) s += __shfl_xor(s, off);
      float inv = 1.f / s;
      float4 o4; o4.x = e0*inv; o4.y = e1*inv; o4.z = e2*inv; o4.w = e3*inv;
      // patch rows n0,n0+1 adjacent -> base + 4*lane is contiguous 1KB
      *(float4*)&att[((size_t)g*NP + n0)*128 + lane*4] = o4;
      if (g == 0) idx0 = mi; else if (g == 1) idx1 = mi; else idx2 = mi;
    }

    // fetch patch-B indices down to lanes 16..31 (executed by all lanes)
    int i0 = __shfl(idx0, srcl);
    int i1 = __shfl(idx1, srcl);
    int i2 = __shfl(idx2, srcl);

    if (lane < 32) {
      // lane 0..15 -> patch n0 elem lane; lane 16..31 -> patch n1 elem lane-16
      float xval = x[(size_t)n0*16 + lane];
      int d = lane & 15;
      float q0 = cbT[0][d][i0];
      float q1 = cbT[1][d][i1];
      float q2 = cbT[2][d][i2];
      xq[(size_t)n0*16 + lane] = (q0 + q1 + q2) * (1.f/3.f);
      float a = q0 - xval, b = q1 - xval, c = q2 - xval;
      lossLocal += a*a + b*b + c*c;
    }
  }
#pragma unroll
  for (int off = 32; off > 0; off >>= 1) lossLocal += __shfl_xor(lossLocal, off);
  if (lane == 0) atomicAdd(lossAcc, lossLocal);
}

// ----------------------------------------------------------------- weight pack
// wp2: [ks=50][lane=64][8 bf16]  k-order (ky,kx,ih); ic = ih*16 + (lane>>5)*8 + j
// wp3: [ks=25][lane=64][8 bf16]  k-order (ky,kx);    ic = (lane>>4)*8 + j
__global__ __launch_bounds__(256) void pack_w_kernel(
    const float* __restrict__ w2, const float* __restrict__ w3,
    __hip_bfloat16* __restrict__ p2, __hip_bfloat16* __restrict__ p3)
{
  int t = blockIdx.x*256 + threadIdx.x;
  if (t < 25600) {
    int ks = t >> 9, l = (t >> 3) & 63, j = t & 7;
    int ky = ks/10, kx = (ks%10)>>1, ih = ks & 1;
    int oc = l & 31, kh = l >> 5;
    int ic = ih*16 + kh*8 + j;
    p2[t] = __float2bfloat16(w2[((oc*32 + ic)*5 + ky)*5 + kx]);
  }
  if (t < 12800) {
    int ks = t >> 9, l = (t >> 3) & 63, j = t & 7;
    int ky = ks/5, kx = ks%5;
    int oc = l & 15, kh = l >> 4;
    int ic = kh*8 + j;
    p3[t] = __float2bfloat16(w3[((oc*32 + ic)*5 + ky)*5 + kx]);
  }
}

// ---------------------------------------------------------------- conv1 direct
// (128,3,96,96) f32 NCHW -> (128,92,92,32) bf16 NHWC, relu.
__global__ __launch_bounds__(256) void conv1_kernel(
    const float* __restrict__ in, const float* __restrict__ wgt,
    const float* __restrict__ bias, __hip_bfloat16* __restrict__ out)
{
  int tile = blockIdx.x;
  int tx0 = (tile % 3) * 32, ty0 = (tile / 3) * 8;
  int ocg = blockIdx.y, n = blockIdx.z;

  int oc_l = threadIdx.x & 15;
  int slot = threadIdx.x >> 4;        // 0..15
  int rp = slot >> 2, cs = slot & 3;

  __shared__ __align__(16) float ins[3][12][36];
  __shared__ float wl[16][76];
  __shared__ __hip_bfloat16 tb[8][32][16];   // 8KB transpose buffer

  float acc[2][8];
#pragma unroll
  for (int r = 0; r < 2; ++r)
#pragma unroll
    for (int p = 0; p < 8; ++p) acc[r][p] = 0.f;

  for (int t = threadIdx.x; t < 3*12*36; t += 256) {
    int ic = t / (12*36); int r = t % (12*36); int ry = r / 36, rx = r % 36;
    int gy = ty0 + ry, gx = tx0 + rx;
    float v = 0.f;
    if (gy < 96 && gx < 96)
      v = in[(((size_t)n*3 + ic)*96 + gy)*96 + gx];
    ins[ic][ry][rx] = v;
  }
  for (int t = threadIdx.x; t < 16*75; t += 256) {
    int oc = t / 75, r = t % 75;
    wl[oc][r] = wgt[(size_t)(ocg*16 + oc)*75 + r];
  }
  __syncthreads();

#pragma unroll 1
  for (int ic = 0; ic < 3; ++ic) {
#pragma unroll
    for (int ky = 0; ky < 5; ++ky) {
      float wv[5];
#pragma unroll
      for (int kx = 0; kx < 5; ++kx) wv[kx] = wl[oc_l][ic*25 + ky*5 + kx];
#pragma unroll
      for (int rr = 0; rr < 2; ++rr) {
        int ry = 2*rp + rr + ky;
        const float4* rowp = (const float4*)&ins[ic][ry][cs*8];
        float4 a = rowp[0], b = rowp[1], c = rowp[2];
        float iv[12] = {a.x,a.y,a.z,a.w, b.x,b.y,b.z,b.w, c.x,c.y,c.z,c.w};
#pragma unroll
        for (int kx = 0; kx < 5; ++kx)
#pragma unroll
          for (int px = 0; px < 8; ++px)
            acc[rr][px] += iv[px + kx] * wv[kx];
      }
    }
  }
  __syncthreads();

  float bv = bias[ocg*16 + oc_l];
#pragma unroll
  for (int rr = 0; rr < 2; ++rr)
#pragma unroll
    for (int px = 0; px < 8; ++px)
      tb[2*rp + rr][cs*8 + px][oc_l] = __float2bfloat16(fmaxf(acc[rr][px] + bv, 0.f));
  __syncthreads();

  for (int t = threadIdx.x; t < 512; t += 256) {
    int byte = t * 16;
    int row = byte >> 10, col = (byte & 1023) >> 5, half = (byte >> 4) & 1;
    int gy = ty0 + row, gx = tx0 + col;
    if (gy < 92 && gx < 92) {
      *(int4*)((char*)out + ((((size_t)n*92 + gy)*92 + gx)*32 + ocg*16 + half*8)*2) =
          *(const int4*)((const char*)tb + byte);
    }
  }
}

// ------------------------------------------------------------------ conv2 MFMA
// (128,92,92,32) bf16 NHWC -> conv 5x5 (88x88) -> pool -> relu
//   -> (128,44,44,32) bf16 NHWC.
__global__ __launch_bounds__(384) void conv2_mfma(
    const __hip_bfloat16* __restrict__ in, const __hip_bfloat16* __restrict__ wp,
    const float* __restrict__ bias, __hip_bfloat16* __restrict__ out)
{
  __shared__ __align__(16) char lds[8*100*64];   // 51200 B

  int n = blockIdx.y, rg = blockIdx.x;
  int oy0 = rg * 4;
  int tid = threadIdx.x;

  for (int t = tid; t < 3200; t += 384) {
    int row = t / 400, rem = t % 400, px = rem >> 2, g = rem & 3;
    int4 v = make_int4(0,0,0,0);
    if (px < 92)
      v = *(const int4*)(in + (((size_t)n*92 + oy0 + row)*92 + px)*32 + g*8);
    int sb = ((row*100 + px) << 6) + ((g ^ ((px >> 1) & 3)) << 4);
    *(int4*)(lds + sb) = v;
  }
  __syncthreads();

  int wv = tid >> 6, lane = tid & 63;
  int rp = wv & 1, cg = wv >> 1;
  int col = lane & 31, khalf = lane >> 5;
  int ixb = cg*32 + col;

  f32x16 acc0, acc1;
#pragma unroll
  for (int i = 0; i < 16; ++i) { acc0[i] = 0.f; acc1[i] = 0.f; }

#pragma unroll
  for (int ks = 0; ks < 50; ++ks) {
    const int ky = ks/10, kx = (ks%10)>>1, ih = ks & 1;
    short8 av = *(const short8*)(wp + ks*512 + lane*8);
    int ix = ixb + kx;
    int g  = (ih*2 + khalf) ^ ((ix >> 1) & 3);
    {
      int row = 2*rp + 0 + ky;
      short8 bv = *(const short8*)(lds + ((row*100 + ix) << 6) + (g << 4));
      acc0 = __builtin_amdgcn_mfma_f32_32x32x16_bf16(av, bv, acc0, 0, 0, 0);
    }
    {
      int row = 2*rp + 1 + ky;
      short8 bv = *(const short8*)(lds + ((row*100 + ix) << 6) + (g << 4));
      acc1 = __builtin_amdgcn_mfma_f32_32x32x16_bf16(av, bv, acc1, 0, 0, 0);
    }
  }
  __syncthreads();

  {
#pragma unroll
    for (int rq = 0; rq < 4; ++rq) {
      __hip_bfloat16 pv[4];
#pragma unroll
      for (int rr = 0; rr < 4; ++rr) {
        int r = rq*4 + rr;
        float m = fmaxf(acc0[r], acc1[r]);
        float o = __shfl_xor(m, 1);
        float p = fmaxf(m, o);
        int oc = (r & 3) + 8*(r >> 2) + 4*khalf;
        pv[rr] = __float2bfloat16(fmaxf(p + bias[oc], 0.f));
      }
      if ((lane & 1) == 0) {
        int pl = col >> 1;
        *(uint2*)(lds + wv*1024 + pl*64 + (8*rq + 4*khalf)*2) = *(const uint2*)pv;
      }
    }
  }
  __syncthreads();

  if (tid < 384) {
    int byte = tid * 16;
    int w = byte >> 10, r = byte & 1023;
    int pl = r >> 6, ocq = (r & 63) >> 4;
    int pr = rg*2 + (w & 1);
    int pc = (w >> 1)*16 + pl;
    if (pc < 44) {
      *(int4*)(out + (((size_t)n*44 + pr)*44 + pc)*32 + ocq*8) =
          *(const int4*)(lds + byte);
    }
  }
}

// ------------------------------------------------------------------ conv3 MFMA
// (128,44,44,32) bf16 NHWC -> conv 5x5 (40x40) -> pool -> relu
//   -> (128,20,20,16) bf16 NHWC.
__global__ __launch_bounds__(384) void conv3_mfma(
    const __hip_bfloat16* __restrict__ in, const __hip_bfloat16* __restrict__ wp,
    const float* __restrict__ bias, __hip_bfloat16* __restrict__ out)
{
  __shared__ __align__(16) char lds[8*52*64];   // 26624 B

  int n = blockIdx.y, rg = blockIdx.x;
  int oy0 = rg * 4;
  int tid = threadIdx.x;

  for (int t = tid; t < 1664; t += 384) {
    int row = t / 208, rem = t % 208, px = rem >> 2, g = rem & 3;
    int4 v = make_int4(0,0,0,0);
    if (px < 44)
      v = *(const int4*)(in + (((size_t)n*44 + oy0 + row)*44 + px)*32 + g*8);
    int sb = ((row*52 + px) << 6) + ((g ^ ((px >> 1) & 3)) << 4);
    *(int4*)(lds + sb) = v;
  }
  __syncthreads();

  int wv = tid >> 6, lane = tid & 63;
  int rp = wv & 1, cg = wv >> 1;
  int col = lane & 15, kq = lane >> 4;
  int ixb = cg*16 + col;

  f32x4 acc0, acc1;
#pragma unroll
  for (int i = 0; i < 4; ++i) { acc0[i] = 0.f; acc1[i] = 0.f; }

#pragma unroll
  for (int ks = 0; ks < 25; ++ks) {
    const int ky = ks/5, kx = ks%5;
    short8 av = *(const short8*)(wp + ks*512 + lane*8);
    int ix = ixb + kx;
    int g  = kq ^ ((ix >> 1) & 3);
    {
      int row = 2*rp + 0 + ky;
      short8 bv = *(const short8*)(lds + ((row*52 + ix) << 6) + (g << 4));
      acc0 = __builtin_amdgcn_mfma_f32_16x16x32_bf16(av, bv, acc0, 0, 0, 0);
    }
    {
      int row = 2*rp + 1 + ky;
      short8 bv = *(const short8*)(lds + ((row*52 + ix) << 6) + (g << 4));
      acc1 = __builtin_amdgcn_mfma_f32_16x16x32_bf16(av, bv, acc1, 0, 0, 0);
    }
  }
  __syncthreads();

  {
    __hip_bfloat16 pv[4];
#pragma unroll
    for (int r = 0; r < 4; ++r) {
      float m = fmaxf(acc0[r], acc1[r]);
      float o = __shfl_xor(m, 1);
      float p = fmaxf(m, o);
      int oc = kq*4 + r;
      pv[r] = __float2bfloat16(fmaxf(p + bias[oc], 0.f));
    }
    if ((lane & 1) == 0) {
      int pl = col >> 1;
      *(uint2*)(lds + wv*256 + pl*32 + kq*8) = *(const uint2*)pv;
    }
  }
  __syncthreads();

  if (tid < 96) {
    int byte = tid * 16;
    int w = byte >> 8, r = byte & 255;
    int pl = r >> 5, half = (r & 31) >> 4;
    int pr = rg*2 + (w & 1);
    int pc = (w >> 1)*8 + pl;
    if (pc < 20) {
      *(int4*)(out + (((size_t)n*20 + pr)*20 + pc)*16 + half*8) =
          *(const int4*)(lds + byte);
    }
  }
}

// --------------------------------------------------------------------- repack
__global__ __launch_bounds__(256) void repack_y3(
    const __hip_bfloat16* __restrict__ y3, float* __restrict__ y3f)
{
  int t = blockIdx.x*256 + threadIdx.x;
  if (t < 819200) {
    int c = t & 15; int r = t >> 4;
    int x = r % 20; r /= 20;
    int y = r % 20; int m = r / 20;
    y3f[((size_t)m*16 + c)*400 + y*20 + x] = __bfloat162float(y3[t]);
  }
}

// ------------------------------------------------------------------------ fc1
__global__ __launch_bounds__(256) void fc1_partial(
    const float* __restrict__ x, const float* __restrict__ w,
    float* __restrict__ part)
{
  constexpr int KC = 6400 / 16;
  __shared__ float xl[128][16];
  __shared__ float wlds[32][17];
  int nt = blockIdx.x, ks = blockIdx.y;
  int k0 = ks * KC;
  int nl = threadIdx.x & 31;
  int mg = threadIdx.x >> 5;
  float acc[16];
#pragma unroll
  for (int j = 0; j < 16; ++j) acc[j] = 0.f;

  for (int kb = 0; kb < KC; kb += 16) {
    for (int t = threadIdx.x; t < 128*16; t += 256) {
      int m = t >> 4, kk = t & 15;
      xl[m][kk] = x[(size_t)m*6400 + k0 + kb + kk];
    }
    for (int t = threadIdx.x; t < 32*16; t += 256) {
      int nn = t >> 4, kk = t & 15;
      wlds[nn][kk] = w[(size_t)(nt*32 + nn)*6400 + k0 + kb + kk];
    }
    __syncthreads();
#pragma unroll
    for (int kk = 0; kk < 16; ++kk) {
      float wvv = wlds[nl][kk];
#pragma unroll
      for (int j = 0; j < 16; ++j)
        acc[j] += xl[mg + 8*j][kk] * wvv;
    }
    __syncthreads();
  }
#pragma unroll
  for (int j = 0; j < 16; ++j) {
    int m = mg + 8*j;
    part[((size_t)ks*128 + m)*512 + nt*32 + nl] = acc[j];
  }
}

__global__ __launch_bounds__(256) void fc1_reduce(
    const float* __restrict__ part, const float* __restrict__ bias,
    float* __restrict__ y4)
{
  int o = blockIdx.x*256 + threadIdx.x;
  int nn = o & 511;
  float s = 0.f;
#pragma unroll
  for (int ks = 0; ks < 16; ++ks)
    s += part[(size_t)ks*65536 + o];
  y4[o] = fmaxf(s + bias[nn], 0.f);
}

// ------------------------------------------------------------------------ fc2
__global__ __launch_bounds__(256) void fc2_kernel(
    const float* __restrict__ y4, const float* __restrict__ w2,
    const float* __restrict__ b2, float* __restrict__ pred)
{
  int o = blockIdx.x*256 + threadIdx.x;
  if (o >= 1280) return;
  int m = o / 10, c = o % 10;
  float s = 0.f;
  const float* yr = y4 + (size_t)m*512;
  const float* wr = w2 + (size_t)c*512;
#pragma unroll 8
  for (int k = 0; k < 512; ++k) s += yr[k]*wr[k];
  pred[o] = s + b2[c];
}

// -------------------------------------------------------------------- epilogue
__global__ void finalize_kernel(const float* __restrict__ lossAcc,
                                float* __restrict__ out)
{
  out[1280] = 2.f * (*lossAcc) / 10616832.f;
  out[84935937] = 0.f;
}

// ---------------------------------------------------------------------- launch
extern "C" void kernel_launch(void* const* d_in, const int* in_sizes, int n_in,
                              void* d_out, int out_size, void* d_ws, size_t ws_size,
                              hipStream_t stream)
{
  const float* x   = (const float*)d_in[0];
  const float* cb  = (const float*)d_in[1];
  const float* w1  = (const float*)d_in[2];
  const float* b1  = (const float*)d_in[3];
  const float* w2  = (const float*)d_in[4];
  const float* b2  = (const float*)d_in[5];
  const float* w3  = (const float*)d_in[6];
  const float* b3  = (const float*)d_in[7];
  const float* wf1 = (const float*)d_in[8];
  const float* bf1 = (const float*)d_in[9];
  const float* wf2 = (const float*)d_in[10];
  const float* bf2 = (const float*)d_in[11];

  float* out = (float*)d_out;
  char*  ws  = (char*)d_ws;

  float*          xq   = (float*)         (ws + 0);
  __hip_bfloat16* y1   = (__hip_bfloat16*)(ws + 14155776);
  __hip_bfloat16* y2   = (__hip_bfloat16*)(ws + 83492864);
  __hip_bfloat16* y3   = (__hip_bfloat16*)(ws + 99352576);
  float*          y3f  = (float*)         (ws + 100990976);
  float*          part = (float*)         (ws + 104267776);
  float*          y4   = (float*)         (ws + 108462080);
  __hip_bfloat16* wp2  = (__hip_bfloat16*)(ws + 108724224);
  __hip_bfloat16* wp3  = (__hip_bfloat16*)(ws + 108775424);
  float*          loss = (float*)         (ws + 108801024);

  hipMemsetAsync(loss, 0, sizeof(float), stream);

  quant_kernel<<<1536, 256, 0, stream>>>(x, cb, out + 1281, xq, loss);
  pack_w_kernel<<<100, 256, 0, stream>>>(w2, w3, wp2, wp3);

  conv1_kernel<<<dim3(36, 2, 128), 256, 0, stream>>>(xq, w1, b1, y1);
  conv2_mfma<<<dim3(22, 128), 384, 0, stream>>>(y1, wp2, b2, y2);
  conv3_mfma<<<dim3(10, 128), 384, 0, stream>>>(y2, wp3, b3, y3);

  repack_y3<<<3200, 256, 0, stream>>>(y3, y3f);

  fc1_partial<<<dim3(16, 16), 256, 0, stream>>>(y3f, wf1, part);
  fc1_reduce<<<256, 256, 0, stream>>>(part, bf1, y4);
  fc2_kernel<<<5, 256, 0, stream>>>(y4, wf2, bf2, out);

  finalize_kernel<<<1, 1, 0, stream>>>(loss, out);
}

// Round 7
// 492.474 us; speedup vs baseline: 3.1188x; 1.3299x over previous
//
#include <hip/hip_runtime.h>
#include <hip/hip_bf16.h>

// ---------------------------------------------------------------------------
// CNN_quantize round 6 (resubmit after infra failure): quant v3 =
// lane-per-patch, scalar(uniform) codebook loads, no shuffles, 2-pass softmax
// (no max-sub), per-wave LDS transpose for coalesced att stores.
// conv1 direct f32 -> bf16 NHWC; conv2/conv3 MFMA bf16; fc1/fc2 f32.
//
// Output layout (floats): [0,1280) pred; [1280] extra_loss;
// [1281,1281+84934656) att(3,221184,128); [84935937] contrastive.
//
// Workspace (byte offsets):
//   xq   f32  @ 0           14,155,776 B   (128,3,96,96)
//   y1   bf16 @ 14,155,776  69,337,088 B   (128,92,92,32) NHWC
//   y2   bf16 @ 83,492,864  15,859,712 B   (128,44,44,32) NHWC
//   y3   bf16 @ 99,352,576   1,638,400 B   (128,20,20,16) NHWC
//   y3f  f32  @ 100,990,976  3,276,800 B   (128,6400) NCHW flat
//   part f32  @ 104,267,776  4,194,304 B
//   y4   f32  @ 108,462,080    262,144 B
//   wp2  bf16 @ 108,724,224     51,200 B
//   wp3  bf16 @ 108,775,424     25,600 B
//   cbn2 f32  @ 108,801,024      1,536 B
//   loss f32  @ 108,802,560          4 B
// ---------------------------------------------------------------------------

#define NP 221184

typedef __attribute__((ext_vector_type(8)))  short  short8;   // 8 bf16
typedef __attribute__((ext_vector_type(16))) float  f32x16;
typedef __attribute__((ext_vector_type(4)))  float  f32x4;

// ---------------------------------------------------------------------- quant
// Grid 864 x 256. Lane owns one patch; k-loop over 128 codes per group.
// Codebook row + cbn2[k] are wave-uniform -> scalar loads. No cross-lane ops
// in the hot loop. att staged per-wave in LDS, stored as 128B segments.
__global__ __launch_bounds__(256) void quant_v3(
    const float* __restrict__ x, const float* __restrict__ cb,
    const float* __restrict__ cbn2,
    float* __restrict__ att, float* __restrict__ xq, float* __restrict__ lossAcc)
{
  __shared__ float stage[4][64][33];   // 34,848 B; per-wave transpose buffer

  const int tid  = threadIdx.x;
  const int wv   = tid >> 6;
  const int lane = tid & 63;
  const int n    = blockIdx.x*256 + tid;        // patch id (always < NP)
  const int n0w  = blockIdx.x*256 + wv*64;      // wave's base patch

  const float4* xp4 = (const float4*)(x + (size_t)n*16);
  float4 xa = xp4[0], xb = xp4[1], xc = xp4[2], xd = xp4[3];
  float xv[16] = {xa.x,xa.y,xa.z,xa.w, xb.x,xb.y,xb.z,xb.w,
                  xc.x,xc.y,xc.z,xc.w, xd.x,xd.y,xd.z,xd.w};
  float xn2 = 0.f;
#pragma unroll
  for (int d = 0; d < 16; ++d) xn2 += xv[d]*xv[d];

  float xqacc[16];
#pragma unroll
  for (int d = 0; d < 16; ++d) xqacc[d] = 0.f;
  float lossLocal = 0.f;

  const int kkl = lane & 31;
  const int ph  = lane >> 5;

#pragma unroll 1
  for (int g = 0; g < 3; ++g) {
    const float* cg  = cb + g*2048;     // [128][16]
    const float* c2g = cbn2 + g*128;

    // ---- pass 1: argmin + softmax denominator (no max-sub; d2 >= 0)
    float mv = 3.4e38f; int mi = 0;
    float s = 0.f;
#pragma unroll 4
    for (int k = 0; k < 128; ++k) {
      const float4* cr = (const float4*)(cg + k*16);
      float4 c0 = cr[0], c1 = cr[1], c2 = cr[2], c3 = cr[3];
      float p0 = fmaf(xv[0],c0.x, fmaf(xv[1],c0.y, fmaf(xv[2],c0.z, xv[3]*c0.w)));
      float p1 = fmaf(xv[4],c1.x, fmaf(xv[5],c1.y, fmaf(xv[6],c1.z, xv[7]*c1.w)));
      float p2 = fmaf(xv[8],c2.x, fmaf(xv[9],c2.y, fmaf(xv[10],c2.z, xv[11]*c2.w)));
      float p3 = fmaf(xv[12],c3.x, fmaf(xv[13],c3.y, fmaf(xv[14],c3.z, xv[15]*c3.w)));
      float dot = (p0+p1)+(p2+p3);
      float d2 = xn2 - 2.f*dot + c2g[k];
      s += __expf(-d2);
      if (d2 < mv) { mv = d2; mi = k; }   // strict < -> lowest index on ties
    }
    float inv = 1.f / s;

    // ---- pass 2: recompute att in 32-k chunks, LDS transpose, coalesced store
#pragma unroll 1
    for (int kc = 0; kc < 4; ++kc) {
#pragma unroll 4
      for (int kk = 0; kk < 32; ++kk) {
        int k = kc*32 + kk;
        const float4* cr = (const float4*)(cg + k*16);
        float4 c0 = cr[0], c1 = cr[1], c2 = cr[2], c3 = cr[3];
        float p0 = fmaf(xv[0],c0.x, fmaf(xv[1],c0.y, fmaf(xv[2],c0.z, xv[3]*c0.w)));
        float p1 = fmaf(xv[4],c1.x, fmaf(xv[5],c1.y, fmaf(xv[6],c1.z, xv[7]*c1.w)));
        float p2 = fmaf(xv[8],c2.x, fmaf(xv[9],c2.y, fmaf(xv[10],c2.z, xv[11]*c2.w)));
        float p3 = fmaf(xv[12],c3.x, fmaf(xv[13],c3.y, fmaf(xv[14],c3.z, xv[15]*c3.w)));
        float dot = (p0+p1)+(p2+p3);
        float d2 = xn2 - 2.f*dot + c2g[k];
        stage[wv][lane][kk] = __expf(-d2) * inv;     // conflict-free (pad 33)
      }
      __builtin_amdgcn_wave_barrier();   // order LDS writes before reads (same wave)
      float* ab = att + ((size_t)g*NP + n0w)*128 + kc*32;
#pragma unroll 8
      for (int i = 0; i < 32; ++i) {
        int p = ph + 2*i;
        ab[(size_t)p*128 + kkl] = stage[wv][p][kkl]; // 2x128B segments/instr
      }
      __builtin_amdgcn_wave_barrier();   // reads done before next chunk writes
    }

    // ---- gather chosen code (per-lane idx, L2-hot)
    const float4* qr = (const float4*)(cg + mi*16);
    float4 q0 = qr[0], q1 = qr[1], q2 = qr[2], q3 = qr[3];
    float qv[16] = {q0.x,q0.y,q0.z,q0.w, q1.x,q1.y,q1.z,q1.w,
                    q2.x,q2.y,q2.z,q2.w, q3.x,q3.y,q3.z,q3.w};
#pragma unroll
    for (int d = 0; d < 16; ++d) {
      xqacc[d] += qv[d];
      float e = qv[d] - xv[d];
      lossLocal += e*e;
    }
  }

  float4* xqo = (float4*)(xq + (size_t)n*16);
  const float third = 1.f/3.f;
  xqo[0] = make_float4(xqacc[0]*third, xqacc[1]*third, xqacc[2]*third, xqacc[3]*third);
  xqo[1] = make_float4(xqacc[4]*third, xqacc[5]*third, xqacc[6]*third, xqacc[7]*third);
  xqo[2] = make_float4(xqacc[8]*third, xqacc[9]*third, xqacc[10]*third, xqacc[11]*third);
  xqo[3] = make_float4(xqacc[12]*third, xqacc[13]*third, xqacc[14]*third, xqacc[15]*third);

#pragma unroll
  for (int off = 32; off > 0; off >>= 1) lossLocal += __shfl_xor(lossLocal, off);
  if (lane == 0) atomicAdd(lossAcc, lossLocal);
}

// ----------------------------------------------------------------- weight pack
// wp2: [ks=50][lane=64][8 bf16]  k-order (ky,kx,ih); ic = ih*16 + (lane>>5)*8 + j
// wp3: [ks=25][lane=64][8 bf16]  k-order (ky,kx);    ic = (lane>>4)*8 + j
// cbn2: [3*128] = sum_d cb[g][k][d]^2
__global__ __launch_bounds__(256) void pack_w_kernel(
    const float* __restrict__ w2, const float* __restrict__ w3,
    const float* __restrict__ cb,
    __hip_bfloat16* __restrict__ p2, __hip_bfloat16* __restrict__ p3,
    float* __restrict__ cbn2)
{
  int t = blockIdx.x*256 + threadIdx.x;
  if (t < 25600) {
    int ks = t >> 9, l = (t >> 3) & 63, j = t & 7;
    int ky = ks/10, kx = (ks%10)>>1, ih = ks & 1;
    int oc = l & 31, kh = l >> 5;
    int ic = ih*16 + kh*8 + j;
    p2[t] = __float2bfloat16(w2[((oc*32 + ic)*5 + ky)*5 + kx]);
  }
  if (t < 12800) {
    int ks = t >> 9, l = (t >> 3) & 63, j = t & 7;
    int ky = ks/5, kx = ks%5;
    int oc = l & 15, kh = l >> 4;
    int ic = kh*8 + j;
    p3[t] = __float2bfloat16(w3[((oc*32 + ic)*5 + ky)*5 + kx]);
  }
  if (t < 384) {
    float s = 0.f;
#pragma unroll
    for (int d = 0; d < 16; ++d) { float v = cb[t*16 + d]; s += v*v; }
    cbn2[t] = s;
  }
}

// ---------------------------------------------------------------- conv1 direct
// (128,3,96,96) f32 NCHW -> (128,92,92,32) bf16 NHWC, relu.
__global__ __launch_bounds__(256) void conv1_kernel(
    const float* __restrict__ in, const float* __restrict__ wgt,
    const float* __restrict__ bias, __hip_bfloat16* __restrict__ out)
{
  int tile = blockIdx.x;
  int tx0 = (tile % 3) * 32, ty0 = (tile / 3) * 8;
  int ocg = blockIdx.y, n = blockIdx.z;

  int oc_l = threadIdx.x & 15;
  int slot = threadIdx.x >> 4;        // 0..15
  int rp = slot >> 2, cs = slot & 3;

  __shared__ __align__(16) float ins[3][12][36];
  __shared__ float wl[16][76];
  __shared__ __hip_bfloat16 tb[8][32][16];   // 8KB transpose buffer

  float acc[2][8];
#pragma unroll
  for (int r = 0; r < 2; ++r)
#pragma unroll
    for (int p = 0; p < 8; ++p) acc[r][p] = 0.f;

  for (int t = threadIdx.x; t < 3*12*36; t += 256) {
    int ic = t / (12*36); int r = t % (12*36); int ry = r / 36, rx = r % 36;
    int gy = ty0 + ry, gx = tx0 + rx;
    float v = 0.f;
    if (gy < 96 && gx < 96)
      v = in[(((size_t)n*3 + ic)*96 + gy)*96 + gx];
    ins[ic][ry][rx] = v;
  }
  for (int t = threadIdx.x; t < 16*75; t += 256) {
    int oc = t / 75, r = t % 75;
    wl[oc][r] = wgt[(size_t)(ocg*16 + oc)*75 + r];
  }
  __syncthreads();

#pragma unroll 1
  for (int ic = 0; ic < 3; ++ic) {
#pragma unroll
    for (int ky = 0; ky < 5; ++ky) {
      float wv[5];
#pragma unroll
      for (int kx = 0; kx < 5; ++kx) wv[kx] = wl[oc_l][ic*25 + ky*5 + kx];
#pragma unroll
      for (int rr = 0; rr < 2; ++rr) {
        int ry = 2*rp + rr + ky;
        const float4* rowp = (const float4*)&ins[ic][ry][cs*8];
        float4 a = rowp[0], b = rowp[1], c = rowp[2];
        float iv[12] = {a.x,a.y,a.z,a.w, b.x,b.y,b.z,b.w, c.x,c.y,c.z,c.w};
#pragma unroll
        for (int kx = 0; kx < 5; ++kx)
#pragma unroll
          for (int px = 0; px < 8; ++px)
            acc[rr][px] += iv[px + kx] * wv[kx];
      }
    }
  }
  __syncthreads();

  float bv = bias[ocg*16 + oc_l];
#pragma unroll
  for (int rr = 0; rr < 2; ++rr)
#pragma unroll
    for (int px = 0; px < 8; ++px)
      tb[2*rp + rr][cs*8 + px][oc_l] = __float2bfloat16(fmaxf(acc[rr][px] + bv, 0.f));
  __syncthreads();

  for (int t = threadIdx.x; t < 512; t += 256) {
    int byte = t * 16;
    int row = byte >> 10, col = (byte & 1023) >> 5, half = (byte >> 4) & 1;
    int gy = ty0 + row, gx = tx0 + col;
    if (gy < 92 && gx < 92) {
      *(int4*)((char*)out + ((((size_t)n*92 + gy)*92 + gx)*32 + ocg*16 + half*8)*2) =
          *(const int4*)((const char*)tb + byte);
    }
  }
}

// ------------------------------------------------------------------ conv2 MFMA
// (128,92,92,32) bf16 NHWC -> conv 5x5 (88x88) -> pool -> relu
//   -> (128,44,44,32) bf16 NHWC.
__global__ __launch_bounds__(384) void conv2_mfma(
    const __hip_bfloat16* __restrict__ in, const __hip_bfloat16* __restrict__ wp,
    const float* __restrict__ bias, __hip_bfloat16* __restrict__ out)
{
  __shared__ __align__(16) char lds[8*100*64];   // 51200 B

  int n = blockIdx.y, rg = blockIdx.x;
  int oy0 = rg * 4;
  int tid = threadIdx.x;

  for (int t = tid; t < 3200; t += 384) {
    int row = t / 400, rem = t % 400, px = rem >> 2, g = rem & 3;
    int4 v = make_int4(0,0,0,0);
    if (px < 92)
      v = *(const int4*)(in + (((size_t)n*92 + oy0 + row)*92 + px)*32 + g*8);
    int sb = ((row*100 + px) << 6) + ((g ^ ((px >> 1) & 3)) << 4);
    *(int4*)(lds + sb) = v;
  }
  __syncthreads();

  int wv = tid >> 6, lane = tid & 63;
  int rp = wv & 1, cg = wv >> 1;
  int col = lane & 31, khalf = lane >> 5;
  int ixb = cg*32 + col;

  f32x16 acc0, acc1;
#pragma unroll
  for (int i = 0; i < 16; ++i) { acc0[i] = 0.f; acc1[i] = 0.f; }

#pragma unroll
  for (int ks = 0; ks < 50; ++ks) {
    const int ky = ks/10, kx = (ks%10)>>1, ih = ks & 1;
    short8 av = *(const short8*)(wp + ks*512 + lane*8);
    int ix = ixb + kx;
    int g  = (ih*2 + khalf) ^ ((ix >> 1) & 3);
    {
      int row = 2*rp + 0 + ky;
      short8 bv = *(const short8*)(lds + ((row*100 + ix) << 6) + (g << 4));
      acc0 = __builtin_amdgcn_mfma_f32_32x32x16_bf16(av, bv, acc0, 0, 0, 0);
    }
    {
      int row = 2*rp + 1 + ky;
      short8 bv = *(const short8*)(lds + ((row*100 + ix) << 6) + (g << 4));
      acc1 = __builtin_amdgcn_mfma_f32_32x32x16_bf16(av, bv, acc1, 0, 0, 0);
    }
  }
  __syncthreads();

  {
#pragma unroll
    for (int rq = 0; rq < 4; ++rq) {
      __hip_bfloat16 pv[4];
#pragma unroll
      for (int rr = 0; rr < 4; ++rr) {
        int r = rq*4 + rr;
        float m = fmaxf(acc0[r], acc1[r]);
        float o = __shfl_xor(m, 1);
        float p = fmaxf(m, o);
        int oc = (r & 3) + 8*(r >> 2) + 4*khalf;
        pv[rr] = __float2bfloat16(fmaxf(p + bias[oc], 0.f));
      }
      if ((lane & 1) == 0) {
        int pl = col >> 1;
        *(uint2*)(lds + wv*1024 + pl*64 + (8*rq + 4*khalf)*2) = *(const uint2*)pv;
      }
    }
  }
  __syncthreads();

  if (tid < 384) {
    int byte = tid * 16;
    int w = byte >> 10, r = byte & 1023;
    int pl = r >> 6, ocq = (r & 63) >> 4;
    int pr = rg*2 + (w & 1);
    int pc = (w >> 1)*16 + pl;
    if (pc < 44) {
      *(int4*)(out + (((size_t)n*44 + pr)*44 + pc)*32 + ocq*8) =
          *(const int4*)(lds + byte);
    }
  }
}

// ------------------------------------------------------------------ conv3 MFMA
// (128,44,44,32) bf16 NHWC -> conv 5x5 (40x40) -> pool -> relu
//   -> (128,20,20,16) bf16 NHWC.
__global__ __launch_bounds__(384) void conv3_mfma(
    const __hip_bfloat16* __restrict__ in, const __hip_bfloat16* __restrict__ wp,
    const float* __restrict__ bias, __hip_bfloat16* __restrict__ out)
{
  __shared__ __align__(16) char lds[8*52*64];   // 26624 B

  int n = blockIdx.y, rg = blockIdx.x;
  int oy0 = rg * 4;
  int tid = threadIdx.x;

  for (int t = tid; t < 1664; t += 384) {
    int row = t / 208, rem = t % 208, px = rem >> 2, g = rem & 3;
    int4 v = make_int4(0,0,0,0);
    if (px < 44)
      v = *(const int4*)(in + (((size_t)n*44 + oy0 + row)*44 + px)*32 + g*8);
    int sb = ((row*52 + px) << 6) + ((g ^ ((px >> 1) & 3)) << 4);
    *(int4*)(lds + sb) = v;
  }
  __syncthreads();

  int wv = tid >> 6, lane = tid & 63;
  int rp = wv & 1, cg = wv >> 1;
  int col = lane & 15, kq = lane >> 4;
  int ixb = cg*16 + col;

  f32x4 acc0, acc1;
#pragma unroll
  for (int i = 0; i < 4; ++i) { acc0[i] = 0.f; acc1[i] = 0.f; }

#pragma unroll
  for (int ks = 0; ks < 25; ++ks) {
    const int ky = ks/5, kx = ks%5;
    short8 av = *(const short8*)(wp + ks*512 + lane*8);
    int ix = ixb + kx;
    int g  = kq ^ ((ix >> 1) & 3);
    {
      int row = 2*rp + 0 + ky;
      short8 bv = *(const short8*)(lds + ((row*52 + ix) << 6) + (g << 4));
      acc0 = __builtin_amdgcn_mfma_f32_16x16x32_bf16(av, bv, acc0, 0, 0, 0);
    }
    {
      int row = 2*rp + 1 + ky;
      short8 bv = *(const short8*)(lds + ((row*52 + ix) << 6) + (g << 4));
      acc1 = __builtin_amdgcn_mfma_f32_16x16x32_bf16(av, bv, acc1, 0, 0, 0);
    }
  }
  __syncthreads();

  {
    __hip_bfloat16 pv[4];
#pragma unroll
    for (int r = 0; r < 4; ++r) {
      float m = fmaxf(acc0[r], acc1[r]);
      float o = __shfl_xor(m, 1);
      float p = fmaxf(m, o);
      int oc = kq*4 + r;
      pv[r] = __float2bfloat16(fmaxf(p + bias[oc], 0.f));
    }
    if ((lane & 1) == 0) {
      int pl = col >> 1;
      *(uint2*)(lds + wv*256 + pl*32 + kq*8) = *(const uint2*)pv;
    }
  }
  __syncthreads();

  if (tid < 96) {
    int byte = tid * 16;
    int w = byte >> 8, r = byte & 255;
    int pl = r >> 5, half = (r & 31) >> 4;
    int pr = rg*2 + (w & 1);
    int pc = (w >> 1)*8 + pl;
    if (pc < 20) {
      *(int4*)(out + (((size_t)n*20 + pr)*20 + pc)*16 + half*8) =
          *(const int4*)(lds + byte);
    }
  }
}

// --------------------------------------------------------------------- repack
__global__ __launch_bounds__(256) void repack_y3(
    const __hip_bfloat16* __restrict__ y3, float* __restrict__ y3f)
{
  int t = blockIdx.x*256 + threadIdx.x;
  if (t < 819200) {
    int c = t & 15; int r = t >> 4;
    int x = r % 20; r /= 20;
    int y = r % 20; int m = r / 20;
    y3f[((size_t)m*16 + c)*400 + y*20 + x] = __bfloat162float(y3[t]);
  }
}

// ------------------------------------------------------------------------ fc1
__global__ __launch_bounds__(256) void fc1_partial(
    const float* __restrict__ x, const float* __restrict__ w,
    float* __restrict__ part)
{
  constexpr int KC = 6400 / 16;
  __shared__ float xl[128][16];
  __shared__ float wlds[32][17];
  int nt = blockIdx.x, ks = blockIdx.y;
  int k0 = ks * KC;
  int nl = threadIdx.x & 31;
  int mg = threadIdx.x >> 5;
  float acc[16];
#pragma unroll
  for (int j = 0; j < 16; ++j) acc[j] = 0.f;

  for (int kb = 0; kb < KC; kb += 16) {
    for (int t = threadIdx.x; t < 128*16; t += 256) {
      int m = t >> 4, kk = t & 15;
      xl[m][kk] = x[(size_t)m*6400 + k0 + kb + kk];
    }
    for (int t = threadIdx.x; t < 32*16; t += 256) {
      int nn = t >> 4, kk = t & 15;
      wlds[nn][kk] = w[(size_t)(nt*32 + nn)*6400 + k0 + kb + kk];
    }
    __syncthreads();
#pragma unroll
    for (int kk = 0; kk < 16; ++kk) {
      float wvv = wlds[nl][kk];
#pragma unroll
      for (int j = 0; j < 16; ++j)
        acc[j] += xl[mg + 8*j][kk] * wvv;
    }
    __syncthreads();
  }
#pragma unroll
  for (int j = 0; j < 16; ++j) {
    int m = mg + 8*j;
    part[((size_t)ks*128 + m)*512 + nt*32 + nl] = acc[j];
  }
}

__global__ __launch_bounds__(256) void fc1_reduce(
    const float* __restrict__ part, const float* __restrict__ bias,
    float* __restrict__ y4)
{
  int o = blockIdx.x*256 + threadIdx.x;
  int nn = o & 511;
  float s = 0.f;
#pragma unroll
  for (int ks = 0; ks < 16; ++ks)
    s += part[(size_t)ks*65536 + o];
  y4[o] = fmaxf(s + bias[nn], 0.f);
}

// ------------------------------------------------------------------------ fc2
__global__ __launch_bounds__(256) void fc2_kernel(
    const float* __restrict__ y4, const float* __restrict__ w2,
    const float* __restrict__ b2, float* __restrict__ pred)
{
  int o = blockIdx.x*256 + threadIdx.x;
  if (o >= 1280) return;
  int m = o / 10, c = o % 10;
  float s = 0.f;
  const float* yr = y4 + (size_t)m*512;
  const float* wr = w2 + (size_t)c*512;
#pragma unroll 8
  for (int k = 0; k < 512; ++k) s += yr[k]*wr[k];
  pred[o] = s + b2[c];
}

// -------------------------------------------------------------------- epilogue
__global__ void finalize_kernel(const float* __restrict__ lossAcc,
                                float* __restrict__ out)
{
  out[1280] = 2.f * (*lossAcc) / 10616832.f;
  out[84935937] = 0.f;
}

// ---------------------------------------------------------------------- launch
extern "C" void kernel_launch(void* const* d_in, const int* in_sizes, int n_in,
                              void* d_out, int out_size, void* d_ws, size_t ws_size,
                              hipStream_t stream)
{
  const float* x   = (const float*)d_in[0];
  const float* cb  = (const float*)d_in[1];
  const float* w1  = (const float*)d_in[2];
  const float* b1  = (const float*)d_in[3];
  const float* w2  = (const float*)d_in[4];
  const float* b2  = (const float*)d_in[5];
  const float* w3  = (const float*)d_in[6];
  const float* b3  = (const float*)d_in[7];
  const float* wf1 = (const float*)d_in[8];
  const float* bf1 = (const float*)d_in[9];
  const float* wf2 = (const float*)d_in[10];
  const float* bf2 = (const float*)d_in[11];

  float* out = (float*)d_out;
  char*  ws  = (char*)d_ws;

  float*          xq   = (float*)         (ws + 0);
  __hip_bfloat16* y1   = (__hip_bfloat16*)(ws + 14155776);
  __hip_bfloat16* y2   = (__hip_bfloat16*)(ws + 83492864);
  __hip_bfloat16* y3   = (__hip_bfloat16*)(ws + 99352576);
  float*          y3f  = (float*)         (ws + 100990976);
  float*          part = (float*)         (ws + 104267776);
  float*          y4   = (float*)         (ws + 108462080);
  __hip_bfloat16* wp2  = (__hip_bfloat16*)(ws + 108724224);
  __hip_bfloat16* wp3  = (__hip_bfloat16*)(ws + 108775424);
  float*          cbn2 = (float*)         (ws + 108801024);
  float*          loss = (float*)         (ws + 108802560);

  hipMemsetAsync(loss, 0, sizeof(float), stream);

  // pack first: quant needs cbn2, convs need wp2/wp3
  pack_w_kernel<<<100, 256, 0, stream>>>(w2, w3, cb, wp2, wp3, cbn2);

  quant_v3<<<864, 256, 0, stream>>>(x, cb, cbn2, out + 1281, xq, loss);

  conv1_kernel<<<dim3(36, 2, 128), 256, 0, stream>>>(xq, w1, b1, y1);
  conv2_mfma<<<dim3(22, 128), 384, 0, stream>>>(y1, wp2, b2, y2);
  conv3_mfma<<<dim3(10, 128), 384, 0, stream>>>(y2, wp3, b3, y3);

  repack_y3<<<3200, 256, 0, stream>>>(y3, y3f);

  fc1_partial<<<dim3(16, 16), 256, 0, stream>>>(y3f, wf1, part);
  fc1_reduce<<<256, 256, 0, stream>>>(part, bf1, y4);
  fc2_kernel<<<5, 256, 0, stream>>>(y4, wf2, bf2, out);

  finalize_kernel<<<1, 1, 0, stream>>>(loss, out);
}